// Round 1
// baseline (505.863 us; speedup 1.0000x reference)
//
#include <hip/hip_runtime.h>

typedef unsigned int u32;
typedef unsigned short u16;

#define NN 8192
#define FIN 512
#define FOUT 128
#define NH 16
#define BK 64    // h GEMM K-slab (u16 cols)
#define BKA 256  // attn K-slab (ints)

typedef float f32x16 __attribute__((ext_vector_type(16)));
typedef __bf16 bf16x8 __attribute__((ext_vector_type(8)));

union PackAB { u32 u[4]; bf16x8 v; };

__device__ __forceinline__ u32 rne_hi(u32 u) {
  return u + (0x7FFFu + ((u >> 16) & 1u));  // RNE bf16 in high half
}
__device__ __forceinline__ u16 f32_to_bf16(float f) {
  return (u16)(rne_hi(__float_as_uint(f)) >> 16);
}

// ---------------- K0: WT = bf16(W^T) [128][512]; w1s = folded w1.
__global__ __launch_bounds__(256) void prep_kernel(
    const float* __restrict__ W, const float* __restrict__ w1,
    u16* __restrict__ WT, float* __restrict__ w1s) {
  int b = blockIdx.x, t = threadIdx.x;
  if (b < 256) {
    int o = b * 256 + t;
    int n = o >> 9, k = o & 511;
    WT[o] = f32_to_bf16(W[k * FOUT + n]);
  } else {
    for (int e = t; e < NH * FOUT; e += 256) {
      int k = e >> 7, f = e & 127;
      w1s[e] = w1[k * 256 + f] + w1[k * 256 + 128 + f];
    }
  }
}

// ---------------- K1: fused h = x@W (full K=512 per 32-row tile, no Hp),
// then HTf frag-order write + attn-net -> qpart, all from LDS.
__global__ __launch_bounds__(256) void h_fused_kernel(
    const float* __restrict__ x, const u16* __restrict__ WT,
    const float* __restrict__ b1, const float* __restrict__ w21,
    const float* __restrict__ b21, const float* __restrict__ w22,
    const float* __restrict__ b22, const float* __restrict__ w1s,
    u16* __restrict__ HTf, float* __restrict__ qpart) {
  __shared__ union {
    struct { u16 aS[32 * BK]; u16 bS[128 * BK]; } g;  // 20.0 KB
    float hs[32][FOUT + 4];                            // 16.5 KB
  } S;
  __shared__ float w1l[NH][FOUT + 4];
  __shared__ float us[32][NH + 1];
  int t = threadIdx.x;
  int w = t >> 6, l = t & 63;
  int m = l & 31, kh = l >> 5;
  int i0 = blockIdx.x * 32;

  int arow = t >> 4, acol = (t & 15) * 4;
  int ac = (t & 15) >> 1, ah = t & 1;
  int aoff0 = arow * BK + ((ac ^ (arow & 7)) << 3) + ah * 4;
  int aoff1 = (arow + 16) * BK + ((ac ^ ((arow + 16) & 7)) << 3) + ah * 4;
  const float* ap0 = x + (size_t)(i0 + arow) * FIN + acol;
  const float* ap1 = ap0 + (size_t)16 * FIN;
  int hr = t >> 3, hc = t & 7;
  const u16* bp0 = WT + (size_t)hr * FIN + hc * 8;
  int boff[4];
#pragma unroll
  for (int p = 0; p < 4; ++p) {
    int r = hr + 32 * p;
    boff[p] = r * BK + ((hc ^ (r & 7)) << 3);
  }
  int aro = m * BK, am7 = m & 7;
  int nB = w * 32 + m;
  int bro = nB * BK, bm7 = nB & 7;

  // Preload the entire 32x512 x-panel: 16 float4/thread = one 64 KB burst.
  float4 xa[8], xb[8];
#pragma unroll
  for (int o = 0; o < 8; ++o) {
    xa[o] = *(const float4*)(ap0 + o * BK);
    xb[o] = *(const float4*)(ap1 + o * BK);
  }
  uint4 hC[4], hN[4];
#pragma unroll
  for (int j = 0; j < 4; ++j) hC[j] = *(const uint4*)(bp0 + (size_t)(32 * j) * FIN);
  bp0 += BK;

  f32x16 acc;
#pragma unroll
  for (int r = 0; r < 16; ++r) acc[r] = 0.0f;

#pragma unroll
  for (int o = 0; o < 8; ++o) {
    if (o) __syncthreads();
    uint2 w0, w1v;
    w0.x = (rne_hi(__float_as_uint(xa[o].y)) & 0xFFFF0000u) | (rne_hi(__float_as_uint(xa[o].x)) >> 16);
    w0.y = (rne_hi(__float_as_uint(xa[o].w)) & 0xFFFF0000u) | (rne_hi(__float_as_uint(xa[o].z)) >> 16);
    w1v.x = (rne_hi(__float_as_uint(xb[o].y)) & 0xFFFF0000u) | (rne_hi(__float_as_uint(xb[o].x)) >> 16);
    w1v.y = (rne_hi(__float_as_uint(xb[o].w)) & 0xFFFF0000u) | (rne_hi(__float_as_uint(xb[o].z)) >> 16);
    *(uint2*)&S.g.aS[aoff0] = w0;
    *(uint2*)&S.g.aS[aoff1] = w1v;
#pragma unroll
    for (int j = 0; j < 4; ++j) *(uint4*)&S.g.bS[boff[j]] = hC[j];
    __syncthreads();
    if (o + 1 < 8) {
#pragma unroll
      for (int j = 0; j < 4; ++j) hN[j] = *(const uint4*)(bp0 + (size_t)(32 * j) * FIN);
      bp0 += BK;
    }
#pragma unroll
    for (int s = 0; s < BK; s += 16) {
      int cA = (s >> 3) + kh;
      PackAB pa, pb;
      pa.v = *(const bf16x8*)&S.g.aS[aro + ((cA ^ am7) << 3)];
      pb.v = *(const bf16x8*)&S.g.bS[bro + ((cA ^ bm7) << 3)];
      acc = __builtin_amdgcn_mfma_f32_32x32x16_bf16(pa.v, pb.v, acc, 0, 0, 0);
    }
    if (o + 1 < 8) {
#pragma unroll
      for (int j = 0; j < 4; ++j) hC[j] = hN[j];
    }
  }
  __syncthreads();  // last MFMA reads of aS/bS done before hs overwrite
  {
    int col = w * 32 + m;
#pragma unroll
    for (int r = 0; r < 16; ++r) {
      int row = (r & 3) + 8 * (r >> 2) + 4 * kh;
      S.hs[row][col] = acc[r];
    }
  }
  for (int e = t; e < NH * FOUT; e += 256) w1l[e >> 7][e & 127] = w1s[e];
  __syncthreads();
  // HTf in MFMA B-fragment order: idx = ((k16*4 + n/32)*64 + (kh*32 + n%32))*8 + k%8
  {
    int n = t & 127, g2 = t >> 7;
#pragma unroll
    for (int gg = 0; gg < 2; ++gg) {
      int g = g2 + 2 * gg;
      int k16 = (i0 >> 4) + (g >> 1), khh = g & 1;
      u32 p[4];
#pragma unroll
      for (int j = 0; j < 4; ++j) {
        u16 lo = f32_to_bf16(S.hs[g * 8 + 2 * j][n]);
        u16 hi = f32_to_bf16(S.hs[g * 8 + 2 * j + 1][n]);
        p[j] = (u32)lo | ((u32)hi << 16);
      }
      uint4 st; st.x = p[0]; st.y = p[1]; st.z = p[2]; st.w = p[3];
      size_t off = ((size_t)(k16 * 4 + (n >> 5)) * 64 + khh * 32 + (n & 31)) * 8;
      *(uint4*)(HTf + off) = st;
    }
  }
  {
    int i = t >> 3, p = t & 7;
    float s0 = b1[p], s1 = b1[p + 8];
#pragma unroll 4
    for (int f = 0; f < FOUT; ++f) {
      float hv = S.hs[i][f];
      s0 = fmaf(hv, w1l[p][f], s0);
      s1 = fmaf(hv, w1l[p + 8][f], s1);
    }
    us[i][p] = fmaxf(s0, 0.0f);
    us[i][p + 8] = fmaxf(s1, 0.0f);
  }
  __syncthreads();
  if (t < 32) {
    float mu = b21[0], lv = b22[0];
#pragma unroll
    for (int k = 0; k < NH; ++k) {
      mu = fmaf(us[t][k], w21[k], mu);
      lv = fmaf(us[t][k], w22[k], lv);
    }
    float sp = fmaxf(lv, 0.0f) + log1pf(expf(-fabsf(lv)));
    float q = 0.5f * mu * mu - logf(sp);  // 0.5*log2pi terms cancel in qmp
#pragma unroll
    for (int off = 16; off; off >>= 1) q += __shfl_down(q, off);
    if (t == 0) qpart[blockIdx.x] = q;
  }
}

// ---------------- K2: attn, full K=8192 per block (KSA=1), fused epilogue:
// deg in-block, out = elu(S/deg) direct. Block 0 also reduces qpart -> qmp.
// Per-CU BW check: 32 KB slab in flight / ~900 cyc latency = 85 GB/s/CU,
// 3x the 26 GB/s per-CU HBM share -> still HBM-saturating at 1 block/CU.
__global__ __launch_bounds__(256) void attn_kernel(
    const int* __restrict__ adj, const u16* __restrict__ HTf,
    const float* __restrict__ qpart, float* __restrict__ out) {
  __shared__ u16 aS[32 * BKA];  // 16 KB
  __shared__ float dinv[32];
  int t = threadIdx.x;
  int w = t >> 6, l = t & 63;
  int m = l & 31, kh = l >> 5;
  int i0 = blockIdx.x * 32;

  int ar = t >> 3, lc = t & 7;
  const int* apb = adj + (size_t)(i0 + ar) * NN + lc * 4;
  int woff[8];
#pragma unroll
  for (int q = 0; q < 8; ++q) {
    int c = q * 4 + (lc >> 1);
    woff[q] = ar * 256 + (((c ^ ar) & 31) << 3) + (lc & 1) * 4;
  }
  const u16* bp = HTf + (size_t)(w * 64 + l) * 8;

  f32x16 acc;
#pragma unroll
  for (int r = 0; r < 16; ++r) acc[r] = 0.0f;
  u32 degacc = 0;

  const int nslab = NN / BKA;  // 32
  int4 aC[8], aN[8];
#pragma unroll
  for (int q = 0; q < 8; ++q) aC[q] = *(const int4*)(apb + q * 32);
  apb += BKA;

  for (int o = 0; o < nslab; ++o) {
    if (o) __syncthreads();  // previous slab's MFMA reads done
#pragma unroll
    for (int q = 0; q < 8; ++q) {
      u32 p0 = ((u32)aC[q].y << 16) | (u32)aC[q].x;
      u32 p1 = ((u32)aC[q].w << 16) | (u32)aC[q].z;
      degacc += p0 + p1;
      uint2 wv; wv.x = p0 * 0x3F80u; wv.y = p1 * 0x3F80u;  // {0,1} -> bf16
      *(uint2*)&aS[woff[q]] = wv;
    }
    __syncthreads();
    if (o + 1 < nslab) {  // prefetch next slab; hides under MFMA phase
#pragma unroll
      for (int q = 0; q < 8; ++q) aN[q] = *(const int4*)(apb + q * 32);
      apb += BKA;
    }
    // MFMA phase: 16 steps, B 4-deep register double-buffer
    {
      bf16x8 bF[4];
#pragma unroll
      for (int j = 0; j < 4; ++j) bF[j] = *(const bf16x8*)(bp + j * 2048);
#pragma unroll
      for (int k16 = 0; k16 < 16; k16 += 4) {
        bf16x8 bN[4];
        if (k16 + 4 < 16) {
#pragma unroll
          for (int j = 0; j < 4; ++j)
            bN[j] = *(const bf16x8*)(bp + (k16 + 4 + j) * 2048);
        }
#pragma unroll
        for (int j = 0; j < 4; ++j) {
          int cc = (k16 + j) * 2 + kh;
          PackAB pa;
          pa.v = *(const bf16x8*)&aS[m * 256 + (((cc ^ m) & 31) << 3)];
          acc = __builtin_amdgcn_mfma_f32_32x32x16_bf16(pa.v, bF[j], acc, 0, 0, 0);
        }
#pragma unroll
        for (int j = 0; j < 4; ++j) bF[j] = bN[j];
      }
    }
    bp += (size_t)16 * 2048;
#pragma unroll
    for (int q = 0; q < 8; ++q) aC[q] = aN[q];
  }
  // deg per row (complete: full K in-block), then fused divide+ELU+store.
  u32 d = (degacc & 0xFFFFu) + (degacc >> 16);
  d += __shfl_down(d, 4);
  d += __shfl_down(d, 2);
  d += __shfl_down(d, 1);
  if (lc == 0) dinv[ar] = d ? 1.0f / (float)d : 0.0f;
  __syncthreads();
  int col = w * 32 + m;
#pragma unroll
  for (int r = 0; r < 16; ++r) {
    int row = (r & 3) + 8 * (r >> 2) + 4 * kh;
    float v = acc[r] * dinv[row];
    v = v > 0.0f ? v : expm1f(v);
    out[(size_t)(i0 + row) * FOUT + col] = v;
  }
  if (blockIdx.x == 0 && t < 64) {  // qpart complete (prior dispatch)
    float v = qpart[t] + qpart[t + 64] + qpart[t + 128] + qpart[t + 192];
#pragma unroll
    for (int off = 32; off; off >>= 1) v += __shfl_down(v, off);
    if (t == 0) out[(size_t)NN * FOUT] = v;
  }
}

extern "C" void kernel_launch(void* const* d_in, const int* in_sizes, int n_in,
                              void* d_out, int out_size, void* d_ws, size_t ws_size,
                              hipStream_t stream) {
  (void)in_sizes; (void)n_in; (void)out_size; (void)ws_size;
  const float* x   = (const float*)d_in[0];
  const int*   adj = (const int*)d_in[1];
  const float* W   = (const float*)d_in[2];
  const float* w1  = (const float*)d_in[3];
  const float* b1  = (const float*)d_in[4];
  const float* w21 = (const float*)d_in[5];
  const float* b21 = (const float*)d_in[6];
  const float* w22 = (const float*)d_in[7];
  const float* b22 = (const float*)d_in[8];
  float* out = (float*)d_out;

  // Workspace: ~2.15 MB total (was ~34 MB; Hp/Sp/degw eliminated).
  char* ws = (char*)d_ws;
  u16*   HTf  = (u16*)ws;   ws += (size_t)NN * FOUT * 2;   // 2 MB
  u16*   WT   = (u16*)ws;   ws += (size_t)FOUT * FIN * 2;  // 128 KB
  float* w1s  = (float*)ws; ws += NH * FOUT * 4;           // 8 KB
  float* qpart= (float*)ws;                                // 1 KB

  prep_kernel<<<257, 256, 0, stream>>>(W, w1, WT, w1s);
  h_fused_kernel<<<256, 256, 0, stream>>>(x, WT, b1, w21, b21, w22, b22, w1s, HTf, qpart);
  attn_kernel<<<256, 256, 0, stream>>>(adj, HTf, qpart, out);
}

// Round 3
// 449.914 us; speedup vs baseline: 1.1244x; 1.1244x over previous
//
#include <hip/hip_runtime.h>

typedef unsigned int u32;
typedef unsigned short u16;

#define NN 8192
#define FIN 512
#define FOUT 128
#define NH 16
#define BK 64    // h GEMM K-slab (u16 cols)
#define BKA 256  // attn K-slab (ints)

typedef float f32x16 __attribute__((ext_vector_type(16)));
typedef __bf16 bf16x8 __attribute__((ext_vector_type(8)));

union PackAB { u32 u[4]; bf16x8 v; };

__device__ __forceinline__ u32 rne_hi(u32 u) {
  return u + (0x7FFFu + ((u >> 16) & 1u));  // RNE bf16 in high half
}
__device__ __forceinline__ u16 f32_to_bf16(float f) {
  return (u16)(rne_hi(__float_as_uint(f)) >> 16);
}

// ---------------- K0: WT = bf16(W^T) [128][512]; w1s = folded w1.
__global__ __launch_bounds__(256) void prep_kernel(
    const float* __restrict__ W, const float* __restrict__ w1,
    u16* __restrict__ WT, float* __restrict__ w1s) {
  int b = blockIdx.x, t = threadIdx.x;
  if (b < 256) {
    int o = b * 256 + t;
    int n = o >> 9, k = o & 511;
    WT[o] = f32_to_bf16(W[k * FOUT + n]);
  } else {
    for (int e = t; e < NH * FOUT; e += 256) {
      int k = e >> 7, f = e & 127;
      w1s[e] = w1[k * 256 + f] + w1[k * 256 + 128 + f];
    }
  }
}

// ---------------- K1: fused h = x@W (full K=512 per 32-row tile),
// then HTf frag-order write + attn-net -> qpart, all from LDS.
__global__ __launch_bounds__(256) void h_fused_kernel(
    const float* __restrict__ x, const u16* __restrict__ WT,
    const float* __restrict__ b1, const float* __restrict__ w21,
    const float* __restrict__ b21, const float* __restrict__ w22,
    const float* __restrict__ b22, const float* __restrict__ w1s,
    u16* __restrict__ HTf, float* __restrict__ qpart) {
  __shared__ union {
    struct { u16 aS[32 * BK]; u16 bS[128 * BK]; } g;  // 20.0 KB
    float hs[32][FOUT + 4];                            // 16.5 KB
  } S;
  __shared__ float w1l[NH][FOUT + 4];
  __shared__ float us[32][NH + 1];
  int t = threadIdx.x;
  int w = t >> 6, l = t & 63;
  int m = l & 31, kh = l >> 5;
  int i0 = blockIdx.x * 32;

  int arow = t >> 4, acol = (t & 15) * 4;
  int ac = (t & 15) >> 1, ah = t & 1;
  int aoff0 = arow * BK + ((ac ^ (arow & 7)) << 3) + ah * 4;
  int aoff1 = (arow + 16) * BK + ((ac ^ ((arow + 16) & 7)) << 3) + ah * 4;
  const float* ap0 = x + (size_t)(i0 + arow) * FIN + acol;
  const float* ap1 = ap0 + (size_t)16 * FIN;
  int hr = t >> 3, hc = t & 7;
  const u16* bp0 = WT + (size_t)hr * FIN + hc * 8;
  int boff[4];
#pragma unroll
  for (int p = 0; p < 4; ++p) {
    int r = hr + 32 * p;
    boff[p] = r * BK + ((hc ^ (r & 7)) << 3);
  }
  int aro = m * BK, am7 = m & 7;
  int nB = w * 32 + m;
  int bro = nB * BK, bm7 = nB & 7;

  // Preload the entire 32x512 x-panel: 16 float4/thread = one 64 KB burst.
  float4 xa[8], xb[8];
#pragma unroll
  for (int o = 0; o < 8; ++o) {
    xa[o] = *(const float4*)(ap0 + o * BK);
    xb[o] = *(const float4*)(ap1 + o * BK);
  }
  uint4 hC[4], hN[4];
#pragma unroll
  for (int j = 0; j < 4; ++j) hC[j] = *(const uint4*)(bp0 + (size_t)(32 * j) * FIN);
  bp0 += BK;

  f32x16 acc;
#pragma unroll
  for (int r = 0; r < 16; ++r) acc[r] = 0.0f;

#pragma unroll
  for (int o = 0; o < 8; ++o) {
    if (o) __syncthreads();
    uint2 w0, w1v;
    w0.x = (rne_hi(__float_as_uint(xa[o].y)) & 0xFFFF0000u) | (rne_hi(__float_as_uint(xa[o].x)) >> 16);
    w0.y = (rne_hi(__float_as_uint(xa[o].w)) & 0xFFFF0000u) | (rne_hi(__float_as_uint(xa[o].z)) >> 16);
    w1v.x = (rne_hi(__float_as_uint(xb[o].y)) & 0xFFFF0000u) | (rne_hi(__float_as_uint(xb[o].x)) >> 16);
    w1v.y = (rne_hi(__float_as_uint(xb[o].w)) & 0xFFFF0000u) | (rne_hi(__float_as_uint(xb[o].z)) >> 16);
    *(uint2*)&S.g.aS[aoff0] = w0;
    *(uint2*)&S.g.aS[aoff1] = w1v;
#pragma unroll
    for (int j = 0; j < 4; ++j) *(uint4*)&S.g.bS[boff[j]] = hC[j];
    __syncthreads();
    if (o + 1 < 8) {
#pragma unroll
      for (int j = 0; j < 4; ++j) hN[j] = *(const uint4*)(bp0 + (size_t)(32 * j) * FIN);
      bp0 += BK;
    }
#pragma unroll
    for (int s = 0; s < BK; s += 16) {
      int cA = (s >> 3) + kh;
      PackAB pa, pb;
      pa.v = *(const bf16x8*)&S.g.aS[aro + ((cA ^ am7) << 3)];
      pb.v = *(const bf16x8*)&S.g.bS[bro + ((cA ^ bm7) << 3)];
      acc = __builtin_amdgcn_mfma_f32_32x32x16_bf16(pa.v, pb.v, acc, 0, 0, 0);
    }
    if (o + 1 < 8) {
#pragma unroll
      for (int j = 0; j < 4; ++j) hC[j] = hN[j];
    }
  }
  __syncthreads();  // last MFMA reads of aS/bS done before hs overwrite
  {
    int col = w * 32 + m;
#pragma unroll
    for (int r = 0; r < 16; ++r) {
      int row = (r & 3) + 8 * (r >> 2) + 4 * kh;
      S.hs[row][col] = acc[r];
    }
  }
  for (int e = t; e < NH * FOUT; e += 256) w1l[e >> 7][e & 127] = w1s[e];
  __syncthreads();
  // HTf in MFMA B-fragment order: idx = ((k16*4 + n/32)*64 + (kh*32 + n%32))*8 + k%8
  {
    int n = t & 127, g2 = t >> 7;
#pragma unroll
    for (int gg = 0; gg < 2; ++gg) {
      int g = g2 + 2 * gg;
      int k16 = (i0 >> 4) + (g >> 1), khh = g & 1;
      u32 p[4];
#pragma unroll
      for (int j = 0; j < 4; ++j) {
        u16 lo = f32_to_bf16(S.hs[g * 8 + 2 * j][n]);
        u16 hi = f32_to_bf16(S.hs[g * 8 + 2 * j + 1][n]);
        p[j] = (u32)lo | ((u32)hi << 16);
      }
      uint4 st; st.x = p[0]; st.y = p[1]; st.z = p[2]; st.w = p[3];
      size_t off = ((size_t)(k16 * 4 + (n >> 5)) * 64 + khh * 32 + (n & 31)) * 8;
      *(uint4*)(HTf + off) = st;
    }
  }
  {
    int i = t >> 3, p = t & 7;
    float s0 = b1[p], s1 = b1[p + 8];
#pragma unroll 4
    for (int f = 0; f < FOUT; ++f) {
      float hv = S.hs[i][f];
      s0 = fmaf(hv, w1l[p][f], s0);
      s1 = fmaf(hv, w1l[p + 8][f], s1);
    }
    us[i][p] = fmaxf(s0, 0.0f);
    us[i][p + 8] = fmaxf(s1, 0.0f);
  }
  __syncthreads();
  if (t < 32) {
    float mu = b21[0], lv = b22[0];
#pragma unroll
    for (int k = 0; k < NH; ++k) {
      mu = fmaf(us[t][k], w21[k], mu);
      lv = fmaf(us[t][k], w22[k], lv);
    }
    float sp = fmaxf(lv, 0.0f) + log1pf(expf(-fabsf(lv)));
    float q = 0.5f * mu * mu - logf(sp);  // 0.5*log2pi terms cancel in qmp
#pragma unroll
    for (int off = 16; off; off >>= 1) q += __shfl_down(q, off);
    if (t == 0) qpart[blockIdx.x] = q;
  }
}

// ---------------- K2: attn with IN-BLOCK split-K=4. 1024 threads = 16 waves
// (4 groups x 4 waves); group g runs the proven slab loop on K-range
// [g*2048,(g+1)*2048) with its own 16 KB aS region. Combine in LDS, fused
// deg-divide + ELU -> out. RACE FIX vs round 2: full-block barrier between
// the last MFMA phase (which reads aS) and the accumulator dump (which
// overwrites the same aS region).
__global__ __launch_bounds__(1024, 4) void attn_kernel(
    const int* __restrict__ adj, const u16* __restrict__ HTf,
    const float* __restrict__ qpart, float* __restrict__ out) {
  __shared__ u16 aS[4 * 32 * BKA];  // 64 KB; per-group 16 KB (= 32x128 f32 in epilogue)
  __shared__ float degp[4][32];
  int t = threadIdx.x;
  int g = t >> 8, tl = t & 255;    // group, thread-in-group
  int w = tl >> 6, l = tl & 63;
  int m = l & 31, kh = l >> 5;
  int i0 = blockIdx.x * 32;
  int k0 = g * (NN / 4);           // 2048 per group

  int ar = tl >> 3, lc = tl & 7;
  const int* apb = adj + (size_t)(i0 + ar) * NN + k0 + lc * 4;
  int goff = g * 32 * BKA;
  int woff[8];
#pragma unroll
  for (int q = 0; q < 8; ++q) {
    int c = q * 4 + (lc >> 1);
    woff[q] = goff + ar * 256 + (((c ^ ar) & 31) << 3) + (lc & 1) * 4;
  }
  const u16* bp = HTf + ((size_t)(k0 >> 4) * 4 * 64 + (size_t)(w * 64 + l)) * 8;

  f32x16 acc;
#pragma unroll
  for (int r = 0; r < 16; ++r) acc[r] = 0.0f;
  u32 degacc = 0;

  const int nslab = (NN / 4) / BKA;  // 8 slabs per group
  int4 aC[8], aN[8];
#pragma unroll
  for (int q = 0; q < 8; ++q) aC[q] = *(const int4*)(apb + q * 32);
  apb += BKA;

  for (int o = 0; o < nslab; ++o) {
    if (o) __syncthreads();  // previous slab's MFMA reads done (all groups lockstep)
#pragma unroll
    for (int q = 0; q < 8; ++q) {
      u32 p0 = ((u32)aC[q].y << 16) | (u32)aC[q].x;
      u32 p1 = ((u32)aC[q].w << 16) | (u32)aC[q].z;
      degacc += p0 + p1;
      uint2 wv; wv.x = p0 * 0x3F80u; wv.y = p1 * 0x3F80u;  // {0,1} -> bf16
      *(uint2*)&aS[woff[q]] = wv;
    }
    __syncthreads();
    if (o + 1 < nslab) {  // prefetch next slab; hides under MFMA phase
#pragma unroll
      for (int q = 0; q < 8; ++q) aN[q] = *(const int4*)(apb + q * 32);
      apb += BKA;
    }
    // MFMA phase: 16 steps, B 4-deep register double-buffer
    {
      bf16x8 bF[4];
#pragma unroll
      for (int j = 0; j < 4; ++j) bF[j] = *(const bf16x8*)(bp + j * 2048);
#pragma unroll
      for (int k16 = 0; k16 < 16; k16 += 4) {
        bf16x8 bN[4];
        if (k16 + 4 < 16) {
#pragma unroll
          for (int j = 0; j < 4; ++j)
            bN[j] = *(const bf16x8*)(bp + (k16 + 4 + j) * 2048);
        }
#pragma unroll
        for (int j = 0; j < 4; ++j) {
          int cc = (k16 + j) * 2 + kh;
          PackAB pa;
          pa.v = *(const bf16x8*)&aS[goff + m * 256 + (((cc ^ m) & 31) << 3)];
          acc = __builtin_amdgcn_mfma_f32_32x32x16_bf16(pa.v, bF[j], acc, 0, 0, 0);
        }
#pragma unroll
        for (int j = 0; j < 4; ++j) bF[j] = bN[j];
      }
    }
    bp += (size_t)16 * 2048;
#pragma unroll
    for (int q = 0; q < 8; ++q) aC[q] = aN[q];
  }
  // Per-group deg partial (16-bit halves packed in degacc).
  u32 d = (degacc & 0xFFFFu) + (degacc >> 16);
  d += __shfl_down(d, 4);
  d += __shfl_down(d, 2);
  d += __shfl_down(d, 1);
  if (lc == 0) degp[g][ar] = (float)d;
  __syncthreads();  // RACE FIX: all waves' MFMA reads of aS complete before dump
  // Dump group accumulator into its own aS region as f32 [32][128].
  {
    float* accS = (float*)&aS[goff];
    int col = w * 32 + m;
#pragma unroll
    for (int r = 0; r < 16; ++r) {
      int row = (r & 3) + 8 * (r >> 2) + 4 * kh;
      accS[row * 128 + col] = acc[r];
    }
  }
  __syncthreads();
  // Combine 4 group partials + deg, fused divide + ELU, store to out.
  {
    int idx = t * 4;            // 1024 threads x 4 = 4096 = 32*128
    int row = idx >> 7;
    const float* r0 = (const float*)aS;
    float4 v0 = *(const float4*)(r0 + idx);
    float4 v1 = *(const float4*)(r0 + 4096 + idx);
    float4 v2 = *(const float4*)(r0 + 8192 + idx);
    float4 v3 = *(const float4*)(r0 + 12288 + idx);
    float deg = degp[0][row] + degp[1][row] + degp[2][row] + degp[3][row];
    float rd = deg != 0.0f ? 1.0f / deg : 0.0f;
    float4 o;
    o.x = (v0.x + v1.x + v2.x + v3.x) * rd;
    o.y = (v0.y + v1.y + v2.y + v3.y) * rd;
    o.z = (v0.z + v1.z + v2.z + v3.z) * rd;
    o.w = (v0.w + v1.w + v2.w + v3.w) * rd;
    o.x = o.x > 0.0f ? o.x : expm1f(o.x);
    o.y = o.y > 0.0f ? o.y : expm1f(o.y);
    o.z = o.z > 0.0f ? o.z : expm1f(o.z);
    o.w = o.w > 0.0f ? o.w : expm1f(o.w);
    *(float4*)(out + (size_t)(i0 + row) * FOUT + (idx & 127)) = o;
  }
  if (blockIdx.x == 0 && t < 64) {  // qpart complete (prior dispatch)
    float v = qpart[t] + qpart[t + 64] + qpart[t + 128] + qpart[t + 192];
#pragma unroll
    for (int off = 32; off; off >>= 1) v += __shfl_down(v, off);
    if (t == 0) out[(size_t)NN * FOUT] = v;
  }
}

extern "C" void kernel_launch(void* const* d_in, const int* in_sizes, int n_in,
                              void* d_out, int out_size, void* d_ws, size_t ws_size,
                              hipStream_t stream) {
  (void)in_sizes; (void)n_in; (void)out_size; (void)ws_size;
  const float* x   = (const float*)d_in[0];
  const int*   adj = (const int*)d_in[1];
  const float* W   = (const float*)d_in[2];
  const float* w1  = (const float*)d_in[3];
  const float* b1  = (const float*)d_in[4];
  const float* w21 = (const float*)d_in[5];
  const float* b21 = (const float*)d_in[6];
  const float* w22 = (const float*)d_in[7];
  const float* b22 = (const float*)d_in[8];
  float* out = (float*)d_out;

  // Workspace: ~2.15 MB total.
  char* ws = (char*)d_ws;
  u16*   HTf  = (u16*)ws;   ws += (size_t)NN * FOUT * 2;   // 2 MB
  u16*   WT   = (u16*)ws;   ws += (size_t)FOUT * FIN * 2;  // 128 KB
  float* w1s  = (float*)ws; ws += NH * FOUT * 4;           // 8 KB
  float* qpart= (float*)ws;                                // 1 KB

  prep_kernel<<<257, 256, 0, stream>>>(W, w1, WT, w1s);
  h_fused_kernel<<<256, 256, 0, stream>>>(x, WT, b1, w21, b21, w22, b22, w1s, HTf, qpart);
  attn_kernel<<<256, 1024, 0, stream>>>(adj, HTf, qpart, out);
}